// Round 8
// baseline (501.858 us; speedup 1.0000x reference)
//
#include <hip/hip_runtime.h>
#include <hip/hip_fp16.h>
#include <math.h>

// GCN 3-layer: h = relu(Agg(x@W1)+b1); h = relu(Agg(h@W2)+b2); out = Agg(h@W3)+b3
// Agg[i] = dinv[i]^2 * g[i] + sum_{e: dst=i} dinv[src]*dinv[i] * g[src]
// dinv = rsqrt(in_deg + 1)
// GEMMs: MFMA, fp16 hi/lo split (XhWh + XlWh + XhWl) for f32-level accuracy.
// W pre-packed in fragment order; K-loop fully unrolled.
// Activations fp16 for the gather phase; aggregation accumulates f32.
// fill_edges runs in 4 dst-windowed passes so the CSR scatter window is
// L2-resident (kills the 8x write-allocate line amplification).
// agg: 2 nodes per wave, 8B per lane -> 2x outstanding gather bytes.

#define N_NODES 100000
#define N_EDGES 1600000

typedef _Float16 f16x8 __attribute__((ext_vector_type(8)));
typedef float    f32x4 __attribute__((ext_vector_type(4)));

// ---------------- preprocessing ----------------

__global__ __launch_bounds__(256) void k_zero_int(int* __restrict__ p, int n) {
    int i = blockIdx.x * 256 + threadIdx.x;
    if (i < n) p[i] = 0;
}

__global__ __launch_bounds__(256) void k_count(const int* __restrict__ dst, int* __restrict__ cnt, int E) {
    int e = blockIdx.x * 256 + threadIdx.x;
    if (e < E) atomicAdd(&cnt[dst[e]], 1);
}

// per-256-block exclusive scan (over 8-padded counts) + block sums
__global__ __launch_bounds__(256) void k_scan_block(const int* __restrict__ cnt, int* __restrict__ excl,
                                                    int* __restrict__ bsum, int n) {
    __shared__ int s[256];
    int i = blockIdx.x * 256 + threadIdx.x;
    int v = (i < n) ? ((cnt[i] + 7) & ~7) : 0;   // padded segment length
    s[threadIdx.x] = v;
    __syncthreads();
    #pragma unroll
    for (int off = 1; off < 256; off <<= 1) {
        int t = (threadIdx.x >= (unsigned)off) ? s[threadIdx.x - off] : 0;
        __syncthreads();
        s[threadIdx.x] += t;
        __syncthreads();
    }
    if (i < n) excl[i] = s[threadIdx.x] - v;
    if (threadIdx.x == 255) bsum[blockIdx.x] = s[255];
}

// single-block exclusive scan over block sums (nb <= 512)
__global__ __launch_bounds__(512) void k_scan_partials(int* __restrict__ bsum, int nb) {
    __shared__ int s[512];
    int tid = threadIdx.x;
    int v = (tid < nb) ? bsum[tid] : 0;
    s[tid] = v;
    __syncthreads();
    #pragma unroll
    for (int off = 1; off < 512; off <<= 1) {
        int t = (tid >= (unsigned)off) ? s[tid - off] : 0;
        __syncthreads();
        s[tid] += t;
        __syncthreads();
    }
    if (tid < nb) bsum[tid] = s[tid] - v;   // exclusive
}

__global__ __launch_bounds__(256) void k_finalize(const int* __restrict__ excl, const int* __restrict__ bsum,
                                                  const int* __restrict__ cnt, int* __restrict__ rowptr,
                                                  int* __restrict__ fill, float* __restrict__ dinv, int n) {
    int i = blockIdx.x * 256 + threadIdx.x;
    if (i < n) {
        int rp = excl[i] + bsum[i >> 8];
        rowptr[i] = rp;     // 8-aligned
        fill[i]   = rp;
        dinv[i]   = rsqrtf((float)(cnt[i] + 1));
    }
}

__global__ __launch_bounds__(256) void k_zero_csr(int2* __restrict__ csr, int n) {
    int i = blockIdx.x * 256 + threadIdx.x;
    if (i < n) csr[i] = make_int2(0, 0);
}

// dst-windowed scatter: only edges with dst in [lo,hi) are placed this pass,
// so the csr write window (~4.6 MB for N/4 nodes) stays L2-resident.
__global__ __launch_bounds__(256) void k_fill_edges(const int* __restrict__ src, const int* __restrict__ dst,
                                                    const float* __restrict__ dinv, int* __restrict__ fill,
                                                    int2* __restrict__ csr, int E, int lo, int hi) {
    int e = blockIdx.x * 256 + threadIdx.x;
    if (e < E) {
        int d = dst[e];
        if (d >= lo && d < hi) {
            int s = src[e];
            int p = atomicAdd(&fill[d], 1);
            csr[p] = make_int2(s, __float_as_int(dinv[s] * dinv[d]));
        }
    }
}

// W pack: fragment-order layout so GEMM B-loads are lane-contiguous.
// Wpk[((c*8+tc)*64 + lane)*8 + i] = fp16(W[k][col]), col=tc*16+(lane&15),
// k=c*32+(lane>>4)*8+i. Lo residual at offset K*128.
__global__ __launch_bounds__(256) void k_wpack(const float* __restrict__ W, _Float16* __restrict__ Wpk, int K) {
    int j = blockIdx.x * 256 + threadIdx.x;
    if (j < K * 128) {
        int i  = j & 7;
        int l  = (j >> 3) & 63;
        int tc = (j >> 9) & 7;
        int c  = j >> 12;
        int col = tc * 16 + (l & 15);
        int k   = c * 32 + (l >> 4) * 8 + i;
        float w = W[(size_t)k * 128 + col];
        _Float16 h = (_Float16)w;
        Wpk[j] = h;
        Wpk[(size_t)K * 128 + j] = (_Float16)(w - (float)h);
    }
}

// ---------------- MFMA GEMM: Y[n,128] = X[n,K] @ W[K,128], fp16 out ----------------
// 4 waves/block, each wave owns 16 rows x 128 cols. No LDS, no barriers.
// A: f32 X rows split to fp16 hi/lo in registers. B: fragment-packed Wpk,
// each load = 64 lanes x 16B contiguous (coalesced, L2-resident).
// Fragment maps (guide §3, m89-verified): A row=lane&15, k=(lane>>4)*8+i;
// B col=lane&15, same k; D col=lane&15, row=(lane>>4)*4+reg.

template <int K>
__global__ __launch_bounds__(256, 3) void k_gemm_mfma(const float* __restrict__ X,
                                                      const _Float16* __restrict__ Wpk,
                                                      _Float16* __restrict__ Y, int n) {
    const int t    = threadIdx.x;
    const int wave = t >> 6;
    const int lane = t & 63;
    const int lrow = lane & 15;
    const int kgrp = lane >> 4;          // 0..3
    const int row0 = blockIdx.x * 64 + wave * 16;
    const int arow = row0 + lrow;
    const bool rok = arow < n;
    const float* __restrict__ xrow = X + (size_t)arow * K;
    const _Float16* __restrict__ Wlo = Wpk + (size_t)K * 128;

    f32x4 acc[8];
    #pragma unroll
    for (int i = 0; i < 8; ++i) acc[i] = (f32x4){0.f, 0.f, 0.f, 0.f};

    #pragma unroll
    for (int c = 0; c < K / 32; ++c) {
        const int k0 = c * 32 + kgrp * 8;
        float4 x0 = make_float4(0.f, 0.f, 0.f, 0.f);
        float4 x1 = make_float4(0.f, 0.f, 0.f, 0.f);
        if (rok) {
            x0 = *(const float4*)&xrow[k0];
            x1 = *(const float4*)&xrow[k0 + 4];
        }
        float xs[8] = {x0.x, x0.y, x0.z, x0.w, x1.x, x1.y, x1.z, x1.w};
        f16x8 ah, al;
        #pragma unroll
        for (int i = 0; i < 8; ++i) {
            _Float16 h = (_Float16)xs[i];
            ah[i] = h;
            al[i] = (_Float16)(xs[i] - (float)h);
        }
        const size_t wb = ((size_t)(c * 8) * 64 + lane) * 8;
        #pragma unroll
        for (int tc = 0; tc < 8; ++tc) {
            f16x8 bh = *(const f16x8*)(Wpk + wb + (size_t)tc * 512);
            f16x8 bl = *(const f16x8*)(Wlo + wb + (size_t)tc * 512);
            acc[tc] = __builtin_amdgcn_mfma_f32_16x16x32_f16(ah, bh, acc[tc], 0, 0, 0);
            acc[tc] = __builtin_amdgcn_mfma_f32_16x16x32_f16(al, bh, acc[tc], 0, 0, 0);
            acc[tc] = __builtin_amdgcn_mfma_f32_16x16x32_f16(ah, bl, acc[tc], 0, 0, 0);
        }
    }

    #pragma unroll
    for (int r = 0; r < 4; ++r) {
        int grow = row0 + kgrp * 4 + r;
        if (grow < n) {
            _Float16* yr = Y + (size_t)grow * 128 + lrow;
            #pragma unroll
            for (int tc = 0; tc < 8; ++tc) yr[tc * 16] = (_Float16)acc[tc][r];
        }
    }
}

// ---------------- aggregation (+ bias, + optional relu) ----------------
// TWO nodes per wave (32 lanes each), grid-stride over node pairs.
// Lane holds 4 features (uint2 = 4 halves) of its half's node -> each gather
// instruction moves 2x256B, doubling outstanding bytes vs 1-node/wave.
// CSR 8-padded, interleaved (src, norm_bits) int2; 8 gathers in flight/half.

template <bool RELU>
__global__ __launch_bounds__(256) void k_agg(const __half* __restrict__ H, const int* __restrict__ rowptr,
                                             const int* __restrict__ cnt, const int2* __restrict__ csr,
                                             const float* __restrict__ dinv, const float* __restrict__ bias,
                                             float* __restrict__ out, int n) {
    const int lane  = threadIdx.x & 63;
    const int half  = lane >> 5;   // which node of the pair
    const int sl    = lane & 31;   // features 4*sl .. 4*sl+3
    const int wave0 = (int)((blockIdx.x * 256 + threadIdx.x) >> 6);
    const int nwave = (int)((gridDim.x * 256) >> 6);
    const uint2* __restrict__ Hu = (const uint2*)H;   // 32 uint2 per row
    const float4 b = *(const float4*)&bias[sl * 4];

    const int npair = n >> 1;   // N even
    for (int p = wave0; p < npair; p += nwave) {
        const int node = p * 2 + half;
        float dv = dinv[node];
        uint2 hu = Hu[(size_t)node * 32 + sl];
        float2 f01 = __half22float2(*(__half2*)&hu.x);
        float2 f23 = __half22float2(*(__half2*)&hu.y);
        float w0 = dv * dv;
        float ax = fmaf(w0, f01.x, b.x);
        float ay = fmaf(w0, f01.y, b.y);
        float az = fmaf(w0, f23.x, b.z);
        float aw = fmaf(w0, f23.y, b.w);

        const int c0 = rowptr[node];
        const int cn = cnt[node];
        for (int e8 = 0; e8 < cn; e8 += 8) {
            const int4* q = (const int4*)(csr + c0 + e8);   // 16B-aligned
            int4 q0 = q[0], q1 = q[1], q2 = q[2], q3 = q[3];
            uint2 u0 = Hu[(size_t)q0.x * 32 + sl];
            uint2 u1 = Hu[(size_t)q0.z * 32 + sl];
            uint2 u2 = Hu[(size_t)q1.x * 32 + sl];
            uint2 u3 = Hu[(size_t)q1.z * 32 + sl];
            uint2 u4 = Hu[(size_t)q2.x * 32 + sl];
            uint2 u5 = Hu[(size_t)q2.z * 32 + sl];
            uint2 u6 = Hu[(size_t)q3.x * 32 + sl];
            uint2 u7 = Hu[(size_t)q3.z * 32 + sl];
            float w0_ = __int_as_float(q0.y), w1_ = __int_as_float(q0.w);
            float w2_ = __int_as_float(q1.y), w3_ = __int_as_float(q1.w);
            float w4_ = __int_as_float(q2.y), w5_ = __int_as_float(q2.w);
            float w6_ = __int_as_float(q3.y), w7_ = __int_as_float(q3.w);
            {
                float2 a01 = __half22float2(*(__half2*)&u0.x), a23 = __half22float2(*(__half2*)&u0.y);
                ax = fmaf(w0_, a01.x, ax); ay = fmaf(w0_, a01.y, ay);
                az = fmaf(w0_, a23.x, az); aw = fmaf(w0_, a23.y, aw);
            }
            {
                float2 a01 = __half22float2(*(__half2*)&u1.x), a23 = __half22float2(*(__half2*)&u1.y);
                ax = fmaf(w1_, a01.x, ax); ay = fmaf(w1_, a01.y, ay);
                az = fmaf(w1_, a23.x, az); aw = fmaf(w1_, a23.y, aw);
            }
            {
                float2 a01 = __half22float2(*(__half2*)&u2.x), a23 = __half22float2(*(__half2*)&u2.y);
                ax = fmaf(w2_, a01.x, ax); ay = fmaf(w2_, a01.y, ay);
                az = fmaf(w2_, a23.x, az); aw = fmaf(w2_, a23.y, aw);
            }
            {
                float2 a01 = __half22float2(*(__half2*)&u3.x), a23 = __half22float2(*(__half2*)&u3.y);
                ax = fmaf(w3_, a01.x, ax); ay = fmaf(w3_, a01.y, ay);
                az = fmaf(w3_, a23.x, az); aw = fmaf(w3_, a23.y, aw);
            }
            {
                float2 a01 = __half22float2(*(__half2*)&u4.x), a23 = __half22float2(*(__half2*)&u4.y);
                ax = fmaf(w4_, a01.x, ax); ay = fmaf(w4_, a01.y, ay);
                az = fmaf(w4_, a23.x, az); aw = fmaf(w4_, a23.y, aw);
            }
            {
                float2 a01 = __half22float2(*(__half2*)&u5.x), a23 = __half22float2(*(__half2*)&u5.y);
                ax = fmaf(w5_, a01.x, ax); ay = fmaf(w5_, a01.y, ay);
                az = fmaf(w5_, a23.x, az); aw = fmaf(w5_, a23.y, aw);
            }
            {
                float2 a01 = __half22float2(*(__half2*)&u6.x), a23 = __half22float2(*(__half2*)&u6.y);
                ax = fmaf(w6_, a01.x, ax); ay = fmaf(w6_, a01.y, ay);
                az = fmaf(w6_, a23.x, az); aw = fmaf(w6_, a23.y, aw);
            }
            {
                float2 a01 = __half22float2(*(__half2*)&u7.x), a23 = __half22float2(*(__half2*)&u7.y);
                ax = fmaf(w7_, a01.x, ax); ay = fmaf(w7_, a01.y, ay);
                az = fmaf(w7_, a23.x, az); aw = fmaf(w7_, a23.y, aw);
            }
        }

        if (RELU) {
            ax = fmaxf(ax, 0.f);
            ay = fmaxf(ay, 0.f);
            az = fmaxf(az, 0.f);
            aw = fmaxf(aw, 0.f);
        }
        *(float4*)&out[(size_t)node * 128 + sl * 4] = make_float4(ax, ay, az, aw);
    }
}

// ---------------- launch ----------------

extern "C" void kernel_launch(void* const* d_in, const int* in_sizes, int n_in,
                              void* d_out, int out_size, void* d_ws, size_t ws_size,
                              hipStream_t stream) {
    const float* x  = (const float*)d_in[0];
    const int*   ei = (const int*)d_in[1];
    const float* W1 = (const float*)d_in[2];
    const float* b1 = (const float*)d_in[3];
    const float* W2 = (const float*)d_in[4];
    const float* b2 = (const float*)d_in[5];
    const float* W3 = (const float*)d_in[6];
    const float* b3 = (const float*)d_in[7];
    float* out = (float*)d_out;

    const int N = N_NODES, E = N_EDGES;
    const int EP = E + 7 * N + 64;   // padded CSR capacity
    const int* src = ei;       // edge_index[0]
    const int* dst = ei + E;   // edge_index[1]

    char* w = (char*)d_ws;
    auto alloc = [&](size_t bytes) -> void* {
        void* p = (void*)w;
        w += (bytes + 255) & ~(size_t)255;
        return p;
    };
    int*      cnt    = (int*)alloc((size_t)N * 4);
    int*      excl   = (int*)alloc((size_t)N * 4);
    int*      bsum   = (int*)alloc(4096);
    int*      rowptr = (int*)alloc((size_t)N * 4);
    int*      fill   = (int*)alloc((size_t)N * 4);
    float*    dinv   = (float*)alloc((size_t)N * 4);
    int2*     csr    = (int2*)alloc((size_t)EP * 8);
    _Float16* Ph     = (_Float16*)alloc((size_t)N * 128 * 2);       // fp16 activations
    _Float16* Wpk    = (_Float16*)alloc((size_t)2 * 256 * 128 * 2); // packed split weights (max K=256)
    float*    Q      = out;  // f32 ping-pong through d_out; rewritten by final layer

    const int nbN = (N + 255) / 256;
    const int nbE = (E + 255) / 256;
    const int nbP = (EP + 255) / 256;

    // CSR build (8-padded segments, zero-filled padding)
    k_zero_int<<<nbN, 256, 0, stream>>>(cnt, N);
    k_count<<<nbE, 256, 0, stream>>>(dst, cnt, E);
    k_scan_block<<<nbN, 256, 0, stream>>>(cnt, excl, bsum, N);
    k_scan_partials<<<1, 512, 0, stream>>>(bsum, nbN);
    k_finalize<<<nbN, 256, 0, stream>>>(excl, bsum, cnt, rowptr, fill, dinv, N);
    k_zero_csr<<<nbP, 256, 0, stream>>>(csr, EP);
    // dst-windowed scatter: 4 passes, each csr window ~4.6 MB (L2-resident)
    for (int r = 0; r < 4; ++r) {
        int lo = r * (N / 4);
        int hi = (r == 3) ? N : (r + 1) * (N / 4);
        k_fill_edges<<<nbE, 256, 0, stream>>>(src, dst, dinv, fill, csr, E, lo, hi);
    }

    const int gemm_grid = (N + 63) / 64;   // 1563
    const int agg_grid  = 2048;

    // layer 1
    k_wpack<<<(256 * 128 + 255) / 256, 256, 0, stream>>>(W1, Wpk, 256);
    k_gemm_mfma<256><<<gemm_grid, 256, 0, stream>>>(x, Wpk, Ph, N);
    k_agg<true><<<agg_grid, 256, 0, stream>>>((const __half*)Ph, rowptr, cnt, csr, dinv, b1, Q, N);
    // layer 2
    k_wpack<<<(128 * 128 + 255) / 256, 256, 0, stream>>>(W2, Wpk, 128);
    k_gemm_mfma<128><<<gemm_grid, 256, 0, stream>>>(Q, Wpk, Ph, N);
    k_agg<true><<<agg_grid, 256, 0, stream>>>((const __half*)Ph, rowptr, cnt, csr, dinv, b2, Q, N);
    // layer 3
    k_wpack<<<(128 * 128 + 255) / 256, 256, 0, stream>>>(W3, Wpk, 128);
    k_gemm_mfma<128><<<gemm_grid, 256, 0, stream>>>(Q, Wpk, Ph, N);
    k_agg<false><<<agg_grid, 256, 0, stream>>>((const __half*)Ph, rowptr, cnt, csr, dinv, b3, out, N);
}

// Round 9
// 491.439 us; speedup vs baseline: 1.0212x; 1.0212x over previous
//
#include <hip/hip_runtime.h>
#include <hip/hip_fp16.h>
#include <math.h>

// GCN 3-layer: h = relu(Agg(x@W1)+b1); h = relu(Agg(h@W2)+b2); out = Agg(h@W3)+b3
// Weight-free aggregation: gemm epilogue writes H'[r] = dinv[r]*(XW)[r] (fp16),
// then out[i] = dinv_i*(H'_i + sum_{j in N(i)} H'_j) + b.  CSR stores src only
// (4 B/edge); padding slots point to zeroed sentinel row N.
// GEMMs: MFMA fp16 hi/lo split (XhWh + XlWh + XhWl), LDS-staged swizzled A tile,
// fragment-packed W.  Aggregation: 4 nodes/wave, uint4 gathers, f32 accum.

#define N_NODES 100000
#define N_EDGES 1600000

typedef _Float16 f16x8 __attribute__((ext_vector_type(8)));
typedef float    f32x4 __attribute__((ext_vector_type(4)));

// ---------------- preprocessing ----------------

__global__ __launch_bounds__(256) void k_zero_int(int* __restrict__ p, int n) {
    int i = blockIdx.x * 256 + threadIdx.x;
    if (i < n) p[i] = 0;
}

__global__ __launch_bounds__(256) void k_count(const int* __restrict__ dst, int* __restrict__ cnt, int E) {
    int e = blockIdx.x * 256 + threadIdx.x;
    if (e < E) atomicAdd(&cnt[dst[e]], 1);
}

// per-256-block exclusive scan (over 8-padded counts) + block sums
__global__ __launch_bounds__(256) void k_scan_block(const int* __restrict__ cnt, int* __restrict__ excl,
                                                    int* __restrict__ bsum, int n) {
    __shared__ int s[256];
    int i = blockIdx.x * 256 + threadIdx.x;
    int v = (i < n) ? ((cnt[i] + 7) & ~7) : 0;   // padded segment length
    s[threadIdx.x] = v;
    __syncthreads();
    #pragma unroll
    for (int off = 1; off < 256; off <<= 1) {
        int t = (threadIdx.x >= (unsigned)off) ? s[threadIdx.x - off] : 0;
        __syncthreads();
        s[threadIdx.x] += t;
        __syncthreads();
    }
    if (i < n) excl[i] = s[threadIdx.x] - v;
    if (threadIdx.x == 255) bsum[blockIdx.x] = s[255];
}

__global__ __launch_bounds__(512) void k_scan_partials(int* __restrict__ bsum, int nb) {
    __shared__ int s[512];
    int tid = threadIdx.x;
    int v = (tid < nb) ? bsum[tid] : 0;
    s[tid] = v;
    __syncthreads();
    #pragma unroll
    for (int off = 1; off < 512; off <<= 1) {
        int t = (tid >= (unsigned)off) ? s[tid - off] : 0;
        __syncthreads();
        s[tid] += t;
        __syncthreads();
    }
    if (tid < nb) bsum[tid] = s[tid] - v;   // exclusive
}

__global__ __launch_bounds__(256) void k_finalize(const int* __restrict__ excl, const int* __restrict__ bsum,
                                                  const int* __restrict__ cnt, int* __restrict__ rowptr,
                                                  int* __restrict__ fill, float* __restrict__ dinv, int n) {
    int i = blockIdx.x * 256 + threadIdx.x;
    if (i < n) {
        int rp = excl[i] + bsum[i >> 8];
        rowptr[i] = rp;     // 8-aligned
        fill[i]   = rp;
        dinv[i]   = rsqrtf((float)(cnt[i] + 1));
    }
}

// init csr to sentinel N (zero row) and zero the sentinel activation row
__global__ __launch_bounds__(256) void k_init_csr(int* __restrict__ csr, int n, unsigned int* __restrict__ phz) {
    int i = blockIdx.x * 256 + threadIdx.x;
    if (i < n) csr[i] = N_NODES;
    if (blockIdx.x == 0 && threadIdx.x < 64) phz[threadIdx.x] = 0;   // 256 B = row N of H'
}

__global__ __launch_bounds__(256) void k_fill_edges(const int* __restrict__ src, const int* __restrict__ dst,
                                                    int* __restrict__ fill, int* __restrict__ csr, int E) {
    int e = blockIdx.x * 256 + threadIdx.x;
    if (e < E) {
        int d = dst[e];
        int p = atomicAdd(&fill[d], 1);
        csr[p] = src[e];
    }
}

// W pack: fragment-order layout so GEMM B-loads are lane-contiguous.
// Wpk[((c*8+tc)*64 + lane)*8 + i] = fp16(W[k][col]), col=tc*16+(lane&15),
// k=c*32+(lane>>4)*8+i. Lo residual at offset K*128.
__global__ __launch_bounds__(256) void k_wpack(const float* __restrict__ W, _Float16* __restrict__ Wpk, int K) {
    int j = blockIdx.x * 256 + threadIdx.x;
    if (j < K * 128) {
        int i  = j & 7;
        int l  = (j >> 3) & 63;
        int tc = (j >> 9) & 7;
        int c  = j >> 12;
        int col = tc * 16 + (l & 15);
        int k   = c * 32 + (l >> 4) * 8 + i;
        float w = W[(size_t)k * 128 + col];
        _Float16 h = (_Float16)w;
        Wpk[j] = h;
        Wpk[(size_t)K * 128 + j] = (_Float16)(w - (float)h);
    }
}

// ---------------- MFMA GEMM: Y[n,128] = dinv * (X[n,K] @ W[K,128]), fp16 out ----
// 4 waves/block, 64 rows/block. A staged through LDS: coalesced float4 global
// loads, col4-XOR swizzle (g ^ (r&7)) on write AND read -> LDS at 8-cy floor.
// Next chunk prefetched to regs before the barrier. B from fragment-packed Wpk.
// Fragment maps (verified rounds 5-8): A row=lane&15, k=(lane>>4)*8+i;
// B col=lane&15, same k; D col=lane&15, row=(lane>>4)*4+reg.

template <int K>
__global__ __launch_bounds__(256) void k_gemm_mfma(const float* __restrict__ X,
                                                   const _Float16* __restrict__ Wpk,
                                                   const float* __restrict__ dinv,
                                                   _Float16* __restrict__ Y, int n) {
    constexpr int NC = K / 32;
    __shared__ float sX[64 * 32];            // 8 KB, float4-slot = r*8 + g (swizzled)
    const int t    = threadIdx.x;
    const int wave = t >> 6;
    const int lane = t & 63;
    const int lrow = lane & 15;
    const int kgrp = lane >> 4;              // 0..3
    const int row0 = blockIdx.x * 64;
    const int R    = wave * 16 + lrow;       // LDS row this lane reads
    const _Float16* __restrict__ Wlo = Wpk + (size_t)K * 128;

    // staging: thread t covers float4-slots f=t and f=t+256 (r = f>>3, g = f&7)
    const int rs0 = t >> 3,        gs = t & 7;
    const int rs1 = (t >> 3) + 32;
    const int gc0 = (gs ^ (rs0 & 7)) << 2;   // swizzled global float col within chunk
    const int gc1 = (gs ^ (rs1 & 7)) << 2;
    const int gr0 = row0 + rs0, gr1 = row0 + rs1;
    const bool ok0 = gr0 < n, ok1 = gr1 < n;
    const float* __restrict__ xr0 = X + (size_t)gr0 * K;
    const float* __restrict__ xr1 = X + (size_t)gr1 * K;

    f32x4 acc[8];
    #pragma unroll
    for (int i = 0; i < 8; ++i) acc[i] = (f32x4){0.f, 0.f, 0.f, 0.f};

    const float4 z4 = make_float4(0.f, 0.f, 0.f, 0.f);
    float4 rv0 = ok0 ? *(const float4*)&xr0[gc0] : z4;
    float4 rv1 = ok1 ? *(const float4*)&xr1[gc1] : z4;
    *(float4*)&sX[(rs0 * 8 + gs) * 4] = rv0;
    *(float4*)&sX[(rs1 * 8 + gs) * 4] = rv1;
    __syncthreads();

    #pragma unroll
    for (int c = 0; c < NC; ++c) {
        if (c + 1 < NC) {   // prefetch next chunk to regs
            rv0 = ok0 ? *(const float4*)&xr0[(c + 1) * 32 + gc0] : z4;
            rv1 = ok1 ? *(const float4*)&xr1[(c + 1) * 32 + gc1] : z4;
        }
        // A fragment from LDS (swizzled)
        float4 x0 = *(const float4*)&sX[(R * 8 + ((kgrp * 2)     ^ (R & 7))) * 4];
        float4 x1 = *(const float4*)&sX[(R * 8 + ((kgrp * 2 + 1) ^ (R & 7))) * 4];
        float xs[8] = {x0.x, x0.y, x0.z, x0.w, x1.x, x1.y, x1.z, x1.w};
        f16x8 ah, al;
        #pragma unroll
        for (int i = 0; i < 8; ++i) {
            _Float16 h = (_Float16)xs[i];
            ah[i] = h;
            al[i] = (_Float16)(xs[i] - (float)h);
        }
        const size_t wb = ((size_t)(c * 8) * 64 + lane) * 8;
        #pragma unroll
        for (int tc = 0; tc < 8; ++tc) {
            f16x8 bh = *(const f16x8*)(Wpk + wb + (size_t)tc * 512);
            f16x8 bl = *(const f16x8*)(Wlo + wb + (size_t)tc * 512);
            acc[tc] = __builtin_amdgcn_mfma_f32_16x16x32_f16(ah, bh, acc[tc], 0, 0, 0);
            acc[tc] = __builtin_amdgcn_mfma_f32_16x16x32_f16(al, bh, acc[tc], 0, 0, 0);
            acc[tc] = __builtin_amdgcn_mfma_f32_16x16x32_f16(ah, bl, acc[tc], 0, 0, 0);
        }
        if (c + 1 < NC) {
            __syncthreads();                 // all waves done reading chunk c
            *(float4*)&sX[(rs0 * 8 + gs) * 4] = rv0;
            *(float4*)&sX[(rs1 * 8 + gs) * 4] = rv1;
            __syncthreads();                 // chunk c+1 visible
        }
    }

    // epilogue: prescale by dinv -> fp16
    #pragma unroll
    for (int r = 0; r < 4; ++r) {
        int grow = row0 + wave * 16 + kgrp * 4 + r;
        if (grow < n) {
            float dv = dinv[grow];
            _Float16* yr = Y + (size_t)grow * 128 + lrow;
            #pragma unroll
            for (int tc = 0; tc < 8; ++tc) yr[tc * 16] = (_Float16)(dv * acc[tc][r]);
        }
    }
}

// ---------------- aggregation (+ bias, + optional relu) ----------------
// FOUR nodes per wave (16 lanes each), grid-stride over node quads.
// Lane holds 8 features (uint4 = 8 halves); 16 lanes cover the 256 B row.
// Each gather instruction touches 4 rows.  Inner loop is pure gather+add
// (weights pre-folded into H'); final scale by dinv_i + bias (+relu).

__device__ __forceinline__ void acc8(float a[8], uint4 u) {
    float2 p;
    p = __half22float2(*(__half2*)&u.x); a[0] += p.x; a[1] += p.y;
    p = __half22float2(*(__half2*)&u.y); a[2] += p.x; a[3] += p.y;
    p = __half22float2(*(__half2*)&u.z); a[4] += p.x; a[5] += p.y;
    p = __half22float2(*(__half2*)&u.w); a[6] += p.x; a[7] += p.y;
}

template <bool RELU>
__global__ __launch_bounds__(256) void k_agg(const __half* __restrict__ H, const int* __restrict__ rowptr,
                                             const int* __restrict__ cnt, const int* __restrict__ csr,
                                             const float* __restrict__ dinv, const float* __restrict__ bias,
                                             float* __restrict__ out, int n) {
    const int lane  = threadIdx.x & 63;
    const int q     = lane >> 4;   // which node of the quad
    const int fl    = lane & 15;   // features 8*fl .. 8*fl+7
    const int wave0 = (int)((blockIdx.x * 256 + threadIdx.x) >> 6);
    const int nwave = (int)((gridDim.x * 256) >> 6);
    const uint4* __restrict__ Hu = (const uint4*)H;   // 16 uint4 per row
    const float4 b0 = *(const float4*)&bias[fl * 8];
    const float4 b1 = *(const float4*)&bias[fl * 8 + 4];

    const int nquad = n >> 2;   // N divisible by 4
    for (int g = wave0; g < nquad; g += nwave) {
        const int node = g * 4 + q;
        float a[8];
        {
            uint4 u = Hu[(size_t)node * 16 + fl];   // self H'_i
            float2 p;
            p = __half22float2(*(__half2*)&u.x); a[0] = p.x; a[1] = p.y;
            p = __half22float2(*(__half2*)&u.y); a[2] = p.x; a[3] = p.y;
            p = __half22float2(*(__half2*)&u.z); a[4] = p.x; a[5] = p.y;
            p = __half22float2(*(__half2*)&u.w); a[6] = p.x; a[7] = p.y;
        }

        const int c0 = rowptr[node];
        const int cn = cnt[node];
        for (int e8 = 0; e8 < cn; e8 += 8) {
            const int4* qp = (const int4*)(csr + c0 + e8);   // 32B-aligned, uniform per quad
            int4 qa = qp[0], qb = qp[1];
            uint4 u0 = Hu[(size_t)qa.x * 16 + fl];
            uint4 u1 = Hu[(size_t)qa.y * 16 + fl];
            uint4 u2 = Hu[(size_t)qa.z * 16 + fl];
            uint4 u3 = Hu[(size_t)qa.w * 16 + fl];
            uint4 u4 = Hu[(size_t)qb.x * 16 + fl];
            uint4 u5 = Hu[(size_t)qb.y * 16 + fl];
            uint4 u6 = Hu[(size_t)qb.z * 16 + fl];
            uint4 u7 = Hu[(size_t)qb.w * 16 + fl];
            acc8(a, u0); acc8(a, u1); acc8(a, u2); acc8(a, u3);
            acc8(a, u4); acc8(a, u5); acc8(a, u6); acc8(a, u7);
        }

        const float dv = dinv[node];
        float4 o0, o1;
        o0.x = fmaf(dv, a[0], b0.x); o0.y = fmaf(dv, a[1], b0.y);
        o0.z = fmaf(dv, a[2], b0.z); o0.w = fmaf(dv, a[3], b0.w);
        o1.x = fmaf(dv, a[4], b1.x); o1.y = fmaf(dv, a[5], b1.y);
        o1.z = fmaf(dv, a[6], b1.z); o1.w = fmaf(dv, a[7], b1.w);
        if (RELU) {
            o0.x = fmaxf(o0.x, 0.f); o0.y = fmaxf(o0.y, 0.f);
            o0.z = fmaxf(o0.z, 0.f); o0.w = fmaxf(o0.w, 0.f);
            o1.x = fmaxf(o1.x, 0.f); o1.y = fmaxf(o1.y, 0.f);
            o1.z = fmaxf(o1.z, 0.f); o1.w = fmaxf(o1.w, 0.f);
        }
        *(float4*)&out[(size_t)node * 128 + fl * 8]     = o0;
        *(float4*)&out[(size_t)node * 128 + fl * 8 + 4] = o1;
    }
}

// ---------------- launch ----------------

extern "C" void kernel_launch(void* const* d_in, const int* in_sizes, int n_in,
                              void* d_out, int out_size, void* d_ws, size_t ws_size,
                              hipStream_t stream) {
    const float* x  = (const float*)d_in[0];
    const int*   ei = (const int*)d_in[1];
    const float* W1 = (const float*)d_in[2];
    const float* b1 = (const float*)d_in[3];
    const float* W2 = (const float*)d_in[4];
    const float* b2 = (const float*)d_in[5];
    const float* W3 = (const float*)d_in[6];
    const float* b3 = (const float*)d_in[7];
    float* out = (float*)d_out;

    const int N = N_NODES, E = N_EDGES;
    const int EP = E + 7 * N + 64;   // padded CSR capacity (4 B entries)
    const int* src = ei;       // edge_index[0]
    const int* dst = ei + E;   // edge_index[1]

    char* w = (char*)d_ws;
    auto alloc = [&](size_t bytes) -> void* {
        void* p = (void*)w;
        w += (bytes + 255) & ~(size_t)255;
        return p;
    };
    int*      cnt    = (int*)alloc((size_t)N * 4);
    int*      excl   = (int*)alloc((size_t)N * 4);
    int*      bsum   = (int*)alloc(4096);
    int*      rowptr = (int*)alloc((size_t)N * 4);
    int*      fill   = (int*)alloc((size_t)N * 4);
    float*    dinv   = (float*)alloc((size_t)N * 4);
    int*      csr    = (int*)alloc((size_t)EP * 4);
    _Float16* Ph     = (_Float16*)alloc((size_t)(N + 8) * 128 * 2);  // fp16 H' + sentinel row N
    _Float16* Wpk    = (_Float16*)alloc((size_t)2 * 256 * 128 * 2);  // packed split weights
    float*    Q      = out;  // f32 ping-pong through d_out; rewritten by final layer

    const int nbN = (N + 255) / 256;
    const int nbE = (E + 255) / 256;
    const int nbP = (EP + 255) / 256;

    // CSR build (8-padded segments; padding -> sentinel row N of H', kept zero)
    k_zero_int<<<nbN, 256, 0, stream>>>(cnt, N);
    k_count<<<nbE, 256, 0, stream>>>(dst, cnt, E);
    k_scan_block<<<nbN, 256, 0, stream>>>(cnt, excl, bsum, N);
    k_scan_partials<<<1, 512, 0, stream>>>(bsum, nbN);
    k_finalize<<<nbN, 256, 0, stream>>>(excl, bsum, cnt, rowptr, fill, dinv, N);
    k_init_csr<<<nbP, 256, 0, stream>>>(csr, EP, (unsigned int*)(Ph + (size_t)N * 128));
    k_fill_edges<<<nbE, 256, 0, stream>>>(src, dst, fill, csr, E);

    const int gemm_grid = (N + 63) / 64;   // 1563
    const int agg_grid  = 2048;

    // layer 1
    k_wpack<<<(256 * 128 + 255) / 256, 256, 0, stream>>>(W1, Wpk, 256);
    k_gemm_mfma<256><<<gemm_grid, 256, 0, stream>>>(x, Wpk, dinv, Ph, N);
    k_agg<true><<<agg_grid, 256, 0, stream>>>((const __half*)Ph, rowptr, cnt, csr, dinv, b1, Q, N);
    // layer 2
    k_wpack<<<(128 * 128 + 255) / 256, 256, 0, stream>>>(W2, Wpk, 128);
    k_gemm_mfma<128><<<gemm_grid, 256, 0, stream>>>(Q, Wpk, dinv, Ph, N);
    k_agg<true><<<agg_grid, 256, 0, stream>>>((const __half*)Ph, rowptr, cnt, csr, dinv, b2, Q, N);
    // layer 3
    k_wpack<<<(128 * 128 + 255) / 256, 256, 0, stream>>>(W3, Wpk, 128);
    k_gemm_mfma<128><<<gemm_grid, 256, 0, stream>>>(Q, Wpk, dinv, Ph, N);
    k_agg<false><<<agg_grid, 256, 0, stream>>>((const __half*)Ph, rowptr, cnt, csr, dinv, b3, out, N);
}

// Round 10
// 464.307 us; speedup vs baseline: 1.0809x; 1.0584x over previous
//
#include <hip/hip_runtime.h>
#include <hip/hip_fp16.h>
#include <math.h>

// GCN 3-layer: h = relu(Agg(x@W1)+b1); h = relu(Agg(h@W2)+b2); out = Agg(h@W3)+b3
// Weight-free aggregation: gemm epilogue writes H'[r] = dinv[r]*(XW)[r] (fp16),
// then out[i] = dinv_i*(H'_i + sum_{j in N(i)} H'_j) + b.  CSR stores src only
// (4 B/edge); padding slots point to zeroed sentinel row N.
// fill_edges: 4 dst-windowed passes -> live scatter region 2.3 MB fits the
// 4 MB per-XCD L2, killing the 16x write-allocate line amplification.
// GEMMs: MFMA fp16 hi/lo split (XhWh + XlWh + XhWl), LDS-staged swizzled A tile,
// fragment-packed W.  Aggregation: 4 nodes/wave, uint4 gathers, f32 accum.

#define N_NODES 100000
#define N_EDGES 1600000

typedef _Float16 f16x8 __attribute__((ext_vector_type(8)));
typedef float    f32x4 __attribute__((ext_vector_type(4)));

// ---------------- preprocessing ----------------

__global__ __launch_bounds__(256) void k_zero_int(int* __restrict__ p, int n) {
    int i = blockIdx.x * 256 + threadIdx.x;
    if (i < n) p[i] = 0;
}

__global__ __launch_bounds__(256) void k_count(const int* __restrict__ dst, int* __restrict__ cnt, int E) {
    int e = blockIdx.x * 256 + threadIdx.x;
    if (e < E) atomicAdd(&cnt[dst[e]], 1);
}

// per-256-block exclusive scan (over 8-padded counts) + block sums
__global__ __launch_bounds__(256) void k_scan_block(const int* __restrict__ cnt, int* __restrict__ excl,
                                                    int* __restrict__ bsum, int n) {
    __shared__ int s[256];
    int i = blockIdx.x * 256 + threadIdx.x;
    int v = (i < n) ? ((cnt[i] + 7) & ~7) : 0;   // padded segment length
    s[threadIdx.x] = v;
    __syncthreads();
    #pragma unroll
    for (int off = 1; off < 256; off <<= 1) {
        int t = (threadIdx.x >= (unsigned)off) ? s[threadIdx.x - off] : 0;
        __syncthreads();
        s[threadIdx.x] += t;
        __syncthreads();
    }
    if (i < n) excl[i] = s[threadIdx.x] - v;
    if (threadIdx.x == 255) bsum[blockIdx.x] = s[255];
}

__global__ __launch_bounds__(512) void k_scan_partials(int* __restrict__ bsum, int nb) {
    __shared__ int s[512];
    int tid = threadIdx.x;
    int v = (tid < nb) ? bsum[tid] : 0;
    s[tid] = v;
    __syncthreads();
    #pragma unroll
    for (int off = 1; off < 512; off <<= 1) {
        int t = (tid >= (unsigned)off) ? s[tid - off] : 0;
        __syncthreads();
        s[tid] += t;
        __syncthreads();
    }
    if (tid < nb) bsum[tid] = s[tid] - v;   // exclusive
}

__global__ __launch_bounds__(256) void k_finalize(const int* __restrict__ excl, const int* __restrict__ bsum,
                                                  const int* __restrict__ cnt, int* __restrict__ rowptr,
                                                  int* __restrict__ fill, float* __restrict__ dinv, int n) {
    int i = blockIdx.x * 256 + threadIdx.x;
    if (i < n) {
        int rp = excl[i] + bsum[i >> 8];
        rowptr[i] = rp;     // 8-aligned
        fill[i]   = rp;
        dinv[i]   = rsqrtf((float)(cnt[i] + 1));
    }
}

// init csr to sentinel N (zero row) and zero the sentinel activation row
__global__ __launch_bounds__(256) void k_init_csr(int* __restrict__ csr, int n, unsigned int* __restrict__ phz) {
    int i = blockIdx.x * 256 + threadIdx.x;
    if (i < n) csr[i] = N_NODES;
    if (blockIdx.x == 0 && threadIdx.x < 64) phz[threadIdx.x] = 0;   // 256 B = row N of H'
}

// dst-windowed scatter: only edges with dst in [lo,hi) are placed this pass,
// so the live csr write region (~2.3 MB) stays resident in each XCD's L2.
__global__ __launch_bounds__(256) void k_fill_edges(const int* __restrict__ src, const int* __restrict__ dst,
                                                    int* __restrict__ fill, int* __restrict__ csr,
                                                    int E, int lo, int hi) {
    int e = blockIdx.x * 256 + threadIdx.x;
    if (e < E) {
        int d = dst[e];
        if (d >= lo && d < hi) {
            int p = atomicAdd(&fill[d], 1);
            csr[p] = src[e];
        }
    }
}

// W pack: fragment-order layout so GEMM B-loads are lane-contiguous.
// Wpk[((c*8+tc)*64 + lane)*8 + i] = fp16(W[k][col]), col=tc*16+(lane&15),
// k=c*32+(lane>>4)*8+i. Lo residual at offset K*128.
__global__ __launch_bounds__(256) void k_wpack(const float* __restrict__ W, _Float16* __restrict__ Wpk, int K) {
    int j = blockIdx.x * 256 + threadIdx.x;
    if (j < K * 128) {
        int i  = j & 7;
        int l  = (j >> 3) & 63;
        int tc = (j >> 9) & 7;
        int c  = j >> 12;
        int col = tc * 16 + (l & 15);
        int k   = c * 32 + (l >> 4) * 8 + i;
        float w = W[(size_t)k * 128 + col];
        _Float16 h = (_Float16)w;
        Wpk[j] = h;
        Wpk[(size_t)K * 128 + j] = (_Float16)(w - (float)h);
    }
}

// ---------------- MFMA GEMM: Y[n,128] = dinv * (X[n,K] @ W[K,128]), fp16 out ----
// 4 waves/block, 64 rows/block. A staged through LDS: coalesced float4 global
// loads, col4-XOR swizzle (g ^ (r&7)) on write AND read. Next chunk prefetched
// to regs before the barrier. B from fragment-packed Wpk.
// Fragment maps (verified rounds 5-9): A row=lane&15, k=(lane>>4)*8+i;
// B col=lane&15, same k; D col=lane&15, row=(lane>>4)*4+reg.

template <int K>
__global__ __launch_bounds__(256) void k_gemm_mfma(const float* __restrict__ X,
                                                   const _Float16* __restrict__ Wpk,
                                                   const float* __restrict__ dinv,
                                                   _Float16* __restrict__ Y, int n) {
    constexpr int NC = K / 32;
    __shared__ float sX[64 * 32];            // 8 KB, float4-slot = r*8 + g (swizzled)
    const int t    = threadIdx.x;
    const int wave = t >> 6;
    const int lane = t & 63;
    const int lrow = lane & 15;
    const int kgrp = lane >> 4;              // 0..3
    const int row0 = blockIdx.x * 64;
    const int R    = wave * 16 + lrow;       // LDS row this lane reads
    const _Float16* __restrict__ Wlo = Wpk + (size_t)K * 128;

    // staging: thread t covers float4-slots f=t and f=t+256 (r = f>>3, g = f&7)
    const int rs0 = t >> 3,        gs = t & 7;
    const int rs1 = (t >> 3) + 32;
    const int gc0 = (gs ^ (rs0 & 7)) << 2;   // swizzled global float col within chunk
    const int gc1 = (gs ^ (rs1 & 7)) << 2;
    const int gr0 = row0 + rs0, gr1 = row0 + rs1;
    const bool ok0 = gr0 < n, ok1 = gr1 < n;
    const float* __restrict__ xr0 = X + (size_t)gr0 * K;
    const float* __restrict__ xr1 = X + (size_t)gr1 * K;

    f32x4 acc[8];
    #pragma unroll
    for (int i = 0; i < 8; ++i) acc[i] = (f32x4){0.f, 0.f, 0.f, 0.f};

    const float4 z4 = make_float4(0.f, 0.f, 0.f, 0.f);
    float4 rv0 = ok0 ? *(const float4*)&xr0[gc0] : z4;
    float4 rv1 = ok1 ? *(const float4*)&xr1[gc1] : z4;
    *(float4*)&sX[(rs0 * 8 + gs) * 4] = rv0;
    *(float4*)&sX[(rs1 * 8 + gs) * 4] = rv1;
    __syncthreads();

    #pragma unroll
    for (int c = 0; c < NC; ++c) {
        if (c + 1 < NC) {   // prefetch next chunk to regs
            rv0 = ok0 ? *(const float4*)&xr0[(c + 1) * 32 + gc0] : z4;
            rv1 = ok1 ? *(const float4*)&xr1[(c + 1) * 32 + gc1] : z4;
        }
        // A fragment from LDS (swizzled)
        float4 x0 = *(const float4*)&sX[(R * 8 + ((kgrp * 2)     ^ (R & 7))) * 4];
        float4 x1 = *(const float4*)&sX[(R * 8 + ((kgrp * 2 + 1) ^ (R & 7))) * 4];
        float xs[8] = {x0.x, x0.y, x0.z, x0.w, x1.x, x1.y, x1.z, x1.w};
        f16x8 ah, al;
        #pragma unroll
        for (int i = 0; i < 8; ++i) {
            _Float16 h = (_Float16)xs[i];
            ah[i] = h;
            al[i] = (_Float16)(xs[i] - (float)h);
        }
        const size_t wb = ((size_t)(c * 8) * 64 + lane) * 8;
        #pragma unroll
        for (int tc = 0; tc < 8; ++tc) {
            f16x8 bh = *(const f16x8*)(Wpk + wb + (size_t)tc * 512);
            f16x8 bl = *(const f16x8*)(Wlo + wb + (size_t)tc * 512);
            acc[tc] = __builtin_amdgcn_mfma_f32_16x16x32_f16(ah, bh, acc[tc], 0, 0, 0);
            acc[tc] = __builtin_amdgcn_mfma_f32_16x16x32_f16(al, bh, acc[tc], 0, 0, 0);
            acc[tc] = __builtin_amdgcn_mfma_f32_16x16x32_f16(ah, bl, acc[tc], 0, 0, 0);
        }
        if (c + 1 < NC) {
            __syncthreads();                 // all waves done reading chunk c
            *(float4*)&sX[(rs0 * 8 + gs) * 4] = rv0;
            *(float4*)&sX[(rs1 * 8 + gs) * 4] = rv1;
            __syncthreads();                 // chunk c+1 visible
        }
    }

    // epilogue: prescale by dinv -> fp16
    #pragma unroll
    for (int r = 0; r < 4; ++r) {
        int grow = row0 + wave * 16 + kgrp * 4 + r;
        if (grow < n) {
            float dv = dinv[grow];
            _Float16* yr = Y + (size_t)grow * 128 + lrow;
            #pragma unroll
            for (int tc = 0; tc < 8; ++tc) yr[tc * 16] = (_Float16)(dv * acc[tc][r]);
        }
    }
}

// ---------------- aggregation (+ bias, + optional relu) ----------------
// FOUR nodes per wave (16 lanes each), grid-stride over node quads.
// Lane holds 8 features (uint4 = 8 halves); 16 lanes cover the 256 B row.
// Inner loop is pure gather+add (weights pre-folded into H').

__device__ __forceinline__ void acc8(float a[8], uint4 u) {
    float2 p;
    p = __half22float2(*(__half2*)&u.x); a[0] += p.x; a[1] += p.y;
    p = __half22float2(*(__half2*)&u.y); a[2] += p.x; a[3] += p.y;
    p = __half22float2(*(__half2*)&u.z); a[4] += p.x; a[5] += p.y;
    p = __half22float2(*(__half2*)&u.w); a[6] += p.x; a[7] += p.y;
}

template <bool RELU>
__global__ __launch_bounds__(256) void k_agg(const __half* __restrict__ H, const int* __restrict__ rowptr,
                                             const int* __restrict__ cnt, const int* __restrict__ csr,
                                             const float* __restrict__ dinv, const float* __restrict__ bias,
                                             float* __restrict__ out, int n) {
    const int lane  = threadIdx.x & 63;
    const int q     = lane >> 4;   // which node of the quad
    const int fl    = lane & 15;   // features 8*fl .. 8*fl+7
    const int wave0 = (int)((blockIdx.x * 256 + threadIdx.x) >> 6);
    const int nwave = (int)((gridDim.x * 256) >> 6);
    const uint4* __restrict__ Hu = (const uint4*)H;   // 16 uint4 per row
    const float4 b0 = *(const float4*)&bias[fl * 8];
    const float4 b1 = *(const float4*)&bias[fl * 8 + 4];

    const int nquad = n >> 2;   // N divisible by 4
    for (int g = wave0; g < nquad; g += nwave) {
        const int node = g * 4 + q;
        float a[8];
        {
            uint4 u = Hu[(size_t)node * 16 + fl];   // self H'_i
            float2 p;
            p = __half22float2(*(__half2*)&u.x); a[0] = p.x; a[1] = p.y;
            p = __half22float2(*(__half2*)&u.y); a[2] = p.x; a[3] = p.y;
            p = __half22float2(*(__half2*)&u.z); a[4] = p.x; a[5] = p.y;
            p = __half22float2(*(__half2*)&u.w); a[6] = p.x; a[7] = p.y;
        }

        const int c0 = rowptr[node];
        const int cn = cnt[node];
        for (int e8 = 0; e8 < cn; e8 += 8) {
            const int4* qp = (const int4*)(csr + c0 + e8);   // 16B-aligned, uniform per quad
            int4 qa = qp[0], qb = qp[1];
            uint4 u0 = Hu[(size_t)qa.x * 16 + fl];
            uint4 u1 = Hu[(size_t)qa.y * 16 + fl];
            uint4 u2 = Hu[(size_t)qa.z * 16 + fl];
            uint4 u3 = Hu[(size_t)qa.w * 16 + fl];
            uint4 u4 = Hu[(size_t)qb.x * 16 + fl];
            uint4 u5 = Hu[(size_t)qb.y * 16 + fl];
            uint4 u6 = Hu[(size_t)qb.z * 16 + fl];
            uint4 u7 = Hu[(size_t)qb.w * 16 + fl];
            acc8(a, u0); acc8(a, u1); acc8(a, u2); acc8(a, u3);
            acc8(a, u4); acc8(a, u5); acc8(a, u6); acc8(a, u7);
        }

        const float dv = dinv[node];
        float4 o0, o1;
        o0.x = fmaf(dv, a[0], b0.x); o0.y = fmaf(dv, a[1], b0.y);
        o0.z = fmaf(dv, a[2], b0.z); o0.w = fmaf(dv, a[3], b0.w);
        o1.x = fmaf(dv, a[4], b1.x); o1.y = fmaf(dv, a[5], b1.y);
        o1.z = fmaf(dv, a[6], b1.z); o1.w = fmaf(dv, a[7], b1.w);
        if (RELU) {
            o0.x = fmaxf(o0.x, 0.f); o0.y = fmaxf(o0.y, 0.f);
            o0.z = fmaxf(o0.z, 0.f); o0.w = fmaxf(o0.w, 0.f);
            o1.x = fmaxf(o1.x, 0.f); o1.y = fmaxf(o1.y, 0.f);
            o1.z = fmaxf(o1.z, 0.f); o1.w = fmaxf(o1.w, 0.f);
        }
        *(float4*)&out[(size_t)node * 128 + fl * 8]     = o0;
        *(float4*)&out[(size_t)node * 128 + fl * 8 + 4] = o1;
    }
}

// ---------------- launch ----------------

extern "C" void kernel_launch(void* const* d_in, const int* in_sizes, int n_in,
                              void* d_out, int out_size, void* d_ws, size_t ws_size,
                              hipStream_t stream) {
    const float* x  = (const float*)d_in[0];
    const int*   ei = (const int*)d_in[1];
    const float* W1 = (const float*)d_in[2];
    const float* b1 = (const float*)d_in[3];
    const float* W2 = (const float*)d_in[4];
    const float* b2 = (const float*)d_in[5];
    const float* W3 = (const float*)d_in[6];
    const float* b3 = (const float*)d_in[7];
    float* out = (float*)d_out;

    const int N = N_NODES, E = N_EDGES;
    const int EP = E + 7 * N + 64;   // padded CSR capacity (4 B entries)
    const int* src = ei;       // edge_index[0]
    const int* dst = ei + E;   // edge_index[1]

    char* w = (char*)d_ws;
    auto alloc = [&](size_t bytes) -> void* {
        void* p = (void*)w;
        w += (bytes + 255) & ~(size_t)255;
        return p;
    };
    int*      cnt    = (int*)alloc((size_t)N * 4);
    int*      excl   = (int*)alloc((size_t)N * 4);
    int*      bsum   = (int*)alloc(4096);
    int*      rowptr = (int*)alloc((size_t)N * 4);
    int*      fill   = (int*)alloc((size_t)N * 4);
    float*    dinv   = (float*)alloc((size_t)N * 4);
    int*      csr    = (int*)alloc((size_t)EP * 4);
    _Float16* Ph     = (_Float16*)alloc((size_t)(N + 8) * 128 * 2);  // fp16 H' + sentinel row N
    _Float16* Wpk    = (_Float16*)alloc((size_t)2 * 256 * 128 * 2);  // packed split weights
    float*    Q      = out;  // f32 ping-pong through d_out; rewritten by final layer

    const int nbN = (N + 255) / 256;
    const int nbE = (E + 255) / 256;
    const int nbP = (EP + 255) / 256;

    // CSR build (8-padded segments; padding -> sentinel row N of H', kept zero)
    k_zero_int<<<nbN, 256, 0, stream>>>(cnt, N);
    k_count<<<nbE, 256, 0, stream>>>(dst, cnt, E);
    k_scan_block<<<nbN, 256, 0, stream>>>(cnt, excl, bsum, N);
    k_scan_partials<<<1, 512, 0, stream>>>(bsum, nbN);
    k_finalize<<<nbN, 256, 0, stream>>>(excl, bsum, cnt, rowptr, fill, dinv, N);
    k_init_csr<<<nbP, 256, 0, stream>>>(csr, EP, (unsigned int*)(Ph + (size_t)N * 128));
    // dst-windowed scatter: 4 passes, live csr region ~2.3 MB (per-XCD-L2-resident)
    for (int r = 0; r < 4; ++r) {
        int lo = r * (N / 4);
        int hi = (r == 3) ? N : (r + 1) * (N / 4);
        k_fill_edges<<<nbE, 256, 0, stream>>>(src, dst, fill, csr, E, lo, hi);
    }

    const int gemm_grid = (N + 63) / 64;   // 1563
    const int agg_grid  = 2048;

    // layer 1
    k_wpack<<<(256 * 128 + 255) / 256, 256, 0, stream>>>(W1, Wpk, 256);
    k_gemm_mfma<256><<<gemm_grid, 256, 0, stream>>>(x, Wpk, dinv, Ph, N);
    k_agg<true><<<agg_grid, 256, 0, stream>>>((const __half*)Ph, rowptr, cnt, csr, dinv, b1, Q, N);
    // layer 2
    k_wpack<<<(128 * 128 + 255) / 256, 256, 0, stream>>>(W2, Wpk, 128);
    k_gemm_mfma<128><<<gemm_grid, 256, 0, stream>>>(Q, Wpk, dinv, Ph, N);
    k_agg<true><<<agg_grid, 256, 0, stream>>>((const __half*)Ph, rowptr, cnt, csr, dinv, b2, Q, N);
    // layer 3
    k_wpack<<<(128 * 128 + 255) / 256, 256, 0, stream>>>(W3, Wpk, 128);
    k_gemm_mfma<128><<<gemm_grid, 256, 0, stream>>>(Q, Wpk, dinv, Ph, N);
    k_agg<false><<<agg_grid, 256, 0, stream>>>((const __half*)Ph, rowptr, cnt, csr, dinv, b3, out, N);
}